// Round 7
// baseline (246.501 us; speedup 1.0000x reference)
//
#include <hip/hip_runtime.h>

#define DMODEL 1024
#define NHEADS 16
#define HDIM   64
#define BB     4
#define TT     2048

typedef __attribute__((ext_vector_type(8))) short bf16x8;
typedef __attribute__((ext_vector_type(4))) short bf16x4;
typedef __attribute__((ext_vector_type(4))) float f32x4;
typedef __attribute__((ext_vector_type(2))) float f32x2;

#if __has_builtin(__builtin_amdgcn_exp2f)
#define EXP2(x) __builtin_amdgcn_exp2f(x)
#else
#define EXP2(x) __expf(0.69314718f * (x))
#endif

// 0.125 * log2(e): folded into Q at projection time
#define C1SCALE 0.18033688f

__device__ inline void async16(const void* g, void* l) {
  __builtin_amdgcn_global_load_lds(
      (const __attribute__((address_space(1))) unsigned int*)g,
      (__attribute__((address_space(3))) unsigned int*)l,
      16, 0, 0);
}

__device__ inline unsigned short f2bf(float x) {
  union { float f; unsigned int u; } c; c.f = x;
  unsigned int r = (c.u + 0x7FFFu + ((c.u >> 16) & 1u)) >> 16;
  return (unsigned short)r;
}

// pack two fp32 -> bf16x2 with RNE rounding (hardware v_cvt_pk_bf16_f32).
// lo16 = bf16(x), hi16 = bf16(y)
__device__ inline unsigned int pkbf_rne(float x, float y) {
  unsigned int r;
  asm("v_cvt_pk_bf16_f32 %0, %1, %2" : "=v"(r) : "v"(x), "v"(y));
  return r;
}

// One fused conversion kernel: x (8192 blk), wq/wk/wv -> wqkvb, wo -> wob (1024 blk each)
__global__ __launch_bounds__(256) void cvt_all(
    const float* __restrict__ x,  const float* __restrict__ wq,
    const float* __restrict__ wk, const float* __restrict__ wv,
    const float* __restrict__ wo,
    unsigned short* __restrict__ xb, unsigned short* __restrict__ wqkvb,
    unsigned short* __restrict__ wob)
{
  int bid = blockIdx.x;
  const float* src; unsigned short* dst; size_t off;
  if (bid < 8192) { src = x; dst = xb; off = (size_t)bid * 1024; }
  else {
    int w = (bid - 8192) >> 10, r = (bid - 8192) & 1023;
    off = (size_t)r * 1024;
    if (w == 0)      { src = wq; dst = wqkvb; }
    else if (w == 1) { src = wk; dst = wqkvb + 1048576; }
    else if (w == 2) { src = wv; dst = wqkvb + 2097152; }
    else             { src = wo; dst = wob; }
  }
  size_t i = off + threadIdx.x * 4;
  float4 v = *(const float4*)(src + i);
  ushort4 o;
  o.x = f2bf(v.x); o.y = f2bf(v.y); o.z = f2bf(v.z); o.w = f2bf(v.w);
  *(ushort4*)(dst + i) = o;
}

// Fused QKV projection: A = xb (8192x1024), W = wqkvb (3072x1024), y = A W^T.
// R8 structure: 8 waves x (32x64 per-wave tile, 32 AGPR acc), BK=64,
// XOR-8 swizzle (conflict-free), double-buffered async staging.
// Grid (64, 24): blockIdx.x = m-tile so same-m blocks (which share the A tile)
// have bids spaced 64 apart -> same XCD under round-robin -> A served from L2.
// Q output pre-scaled by C1SCALE. V-epilogue uses packed ushort4 stores.
__global__ __launch_bounds__(512, 4) void gemm_qkv(
    const unsigned short* __restrict__ A, const unsigned short* __restrict__ W,
    unsigned short* __restrict__ qw, unsigned short* __restrict__ kw,
    unsigned short* __restrict__ vtw)
{
  __shared__ unsigned short As[2][128 * 64];
  __shared__ unsigned short Bs[2][128 * 64];
  const int tid  = threadIdx.x;
  const int lane = tid & 63;
  const int wave = tid >> 6;           // 0..7
  const int lo   = lane & 15, q4 = lane >> 4;
  const int lo7  = lane & 7;
  const int wm   = wave & 3, wn = wave >> 2;  // 32-row quarter, 64-col half
  const int m0 = blockIdx.x * 128;            // m-tile on x (XCD locality)
  const int nb = blockIdx.y;                  // 0..23
  const int n0 = nb * 128;
  const int mid = nb >> 3;

  f32x4 acc[2][4] = {};

  auto stage = [&](int k0, int buf) {
#pragma unroll
    for (int i = 0; i < 2; ++i) {
      int ci = i * 512 + tid;          // 0..1023
      int row = ci >> 3;
      int c = (ci & 7) ^ (row & 7);
      async16(A + (size_t)(m0 + row) * DMODEL + k0 + c * 8, (char*)As[buf] + ci * 16);
      async16(W + (size_t)(n0 + row) * DMODEL + k0 + c * 8, (char*)Bs[buf] + ci * 16);
    }
  };

  stage(0, 0);
  for (int it = 0; it < DMODEL / 64; ++it) {
    const int buf = it & 1;
    __syncthreads();  // stage(it), issued one compute phase ago, now resident
    if (it + 1 < DMODEL / 64) stage((it + 1) * 64, buf ^ 1);
#pragma unroll
    for (int hh = 0; hh < 2; ++hh) {
      bf16x8 af[2], bf[4];
#pragma unroll
      for (int mi = 0; mi < 2; ++mi)
        af[mi] = *(const bf16x8*)&As[buf][(wm * 32 + mi * 16 + lo) * 64 + ((hh * 4 + q4) ^ lo7) * 8];
#pragma unroll
      for (int ni = 0; ni < 4; ++ni)
        bf[ni] = *(const bf16x8*)&Bs[buf][(wn * 64 + ni * 16 + lo) * 64 + ((hh * 4 + q4) ^ lo7) * 8];
#pragma unroll
      for (int mi = 0; mi < 2; ++mi)
#pragma unroll
        for (int ni = 0; ni < 4; ++ni)
          acc[mi][ni] = __builtin_amdgcn_mfma_f32_16x16x32_bf16(af[mi], bf[ni], acc[mi][ni], 0, 0, 0);
    }
  }

  unsigned short* dst = (mid == 0) ? qw : (mid == 1) ? kw : vtw;
  const float sc = (mid == 0) ? C1SCALE : 1.0f;
#pragma unroll
  for (int mi = 0; mi < 2; ++mi) {
#pragma unroll
    for (int ni = 0; ni < 4; ++ni) {
      int m_ = m0 + wm * 32 + mi * 16 + q4 * 4;      // t0 (multiple of 4)
      int nl = ((nb & 7) * 128) + wn * 64 + ni * 16 + lo;
      int b_ = m_ >> 11, t_ = m_ & (TT - 1);
      int h_ = nl >> 6, d_ = nl & 63;
      if (mid == 2) {
        ushort4 o4;
        o4.x = f2bf(acc[mi][ni][0]);
        o4.y = f2bf(acc[mi][ni][1]);
        o4.z = f2bf(acc[mi][ni][2]);
        o4.w = f2bf(acc[mi][ni][3]);
        *(ushort4*)&dst[(((size_t)(b_ * NHEADS + h_)) * HDIM + d_) * TT + t_] = o4;
      } else {
#pragma unroll
        for (int r = 0; r < 4; ++r) {
          float v = acc[mi][ni][r] * sc;
          dst[(((size_t)(b_ * NHEADS + h_)) * TT + t_ + r) * HDIM + d_] = f2bf(v);
        }
      }
    }
  }
}

// Output projection: C = A W^T + bias, fp32 out. Same R8 dbuf structure,
// grid (64, 8) with m on x for XCD locality of the A (ow) tile.
__global__ __launch_bounds__(512, 4) void gemm_out(
    const unsigned short* __restrict__ A, const unsigned short* __restrict__ W,
    const float* __restrict__ bias, float* __restrict__ C)
{
  __shared__ unsigned short As[2][128 * 64];
  __shared__ unsigned short Bs[2][128 * 64];
  const int tid  = threadIdx.x;
  const int lane = tid & 63;
  const int wave = tid >> 6;
  const int lo   = lane & 15, q4 = lane >> 4;
  const int lo7  = lane & 7;
  const int wm   = wave & 3, wn = wave >> 2;
  const int m0 = blockIdx.x * 128, n0 = blockIdx.y * 128;

  f32x4 acc[2][4] = {};

  auto stage = [&](int k0, int buf) {
#pragma unroll
    for (int i = 0; i < 2; ++i) {
      int ci = i * 512 + tid;
      int row = ci >> 3;
      int c = (ci & 7) ^ (row & 7);
      async16(A + (size_t)(m0 + row) * DMODEL + k0 + c * 8, (char*)As[buf] + ci * 16);
      async16(W + (size_t)(n0 + row) * DMODEL + k0 + c * 8, (char*)Bs[buf] + ci * 16);
    }
  };

  stage(0, 0);
  for (int it = 0; it < DMODEL / 64; ++it) {
    const int buf = it & 1;
    __syncthreads();
    if (it + 1 < DMODEL / 64) stage((it + 1) * 64, buf ^ 1);
#pragma unroll
    for (int hh = 0; hh < 2; ++hh) {
      bf16x8 af[2], bf[4];
#pragma unroll
      for (int mi = 0; mi < 2; ++mi)
        af[mi] = *(const bf16x8*)&As[buf][(wm * 32 + mi * 16 + lo) * 64 + ((hh * 4 + q4) ^ lo7) * 8];
#pragma unroll
      for (int ni = 0; ni < 4; ++ni)
        bf[ni] = *(const bf16x8*)&Bs[buf][(wn * 64 + ni * 16 + lo) * 64 + ((hh * 4 + q4) ^ lo7) * 8];
#pragma unroll
      for (int mi = 0; mi < 2; ++mi)
#pragma unroll
        for (int ni = 0; ni < 4; ++ni)
          acc[mi][ni] = __builtin_amdgcn_mfma_f32_16x16x32_bf16(af[mi], bf[ni], acc[mi][ni], 0, 0, 0);
    }
  }

#pragma unroll
  for (int mi = 0; mi < 2; ++mi)
#pragma unroll
    for (int ni = 0; ni < 4; ++ni)
#pragma unroll
      for (int r = 0; r < 4; ++r) {
        int m = m0 + wm * 32 + mi * 16 + q4 * 4 + r;
        int n = n0 + wn * 64 + ni * 16 + lo;
        C[(size_t)m * DMODEL + n] = acc[mi][ni][r] + bias[n];
      }
}

// Flash attention + ALiBi, fixed-scale softmax, register-resident P (S^T trick),
// exact per-head sliding window. 8 waves x 32 q-rows = 256-row Q-block.
// PV at K=32 via permlane 4x4 lane-group transpose; VALU f32 row-sum +
// RNE P-pack. XCD-group swizzle: 8 qb-blocks of each (slot,b) on one XCD.
// htab = r5-verified pairing (equal-duration co-resident pairs).
// Exponent path: per (m-subtile, key-tile) the sign of w = qrow-key is
// wave-uniform except on the <=1 diagonal-overlap tile; uniform cases use
// packed f32x2 adds (v_pk_add_f32): exp2 arg = a -/+ sw +/- skb where
// sw = slopeL*eb (hoisted) and skb = slopeL*kb. Mixed tiles use the exact
// scalar abs path (bit-identical to the r5 formula).
__global__ __launch_bounds__(512, 4) void attn_kernel(
    const unsigned short* __restrict__ Q, const unsigned short* __restrict__ K,
    const unsigned short* __restrict__ Vt, unsigned short* __restrict__ O)
{
  __shared__ unsigned short Ks[2][64 * 64];
  __shared__ unsigned short Vs[2][64 * 64];

  const int tid = threadIdx.x, lane = tid & 63, wave = tid >> 6;  // wave 0..7
  const int lo = lane & 15, q4 = lane >> 4;
  const int lo7 = lane & 7;
  const int bid = blockIdx.x;  // 512 blocks
  // XCD-group decomposition: g = (bid&7) + 8*(bid>>6), qb = (bid>>3)&7
  const int g   = (bid & 7) + 8 * (bid >> 6);   // 0..63 group (slot,b)
  const int qb  = (bid >> 3) & 7;
  const int slot = g >> 2;
  const int b   = g & 3;
  // htab[s] packed as nibbles: {12,13,14,15,11,10,9,8,4,5,6,7,1,0,2,3}
  const int h  = (int)((0x3201765489ABFEDCull >> (slot * 4)) & 15);
  const int bh = b * NHEADS + h;
  const float slopeL = exp2f(-0.5f * (float)(h + 1)) * 1.44269504f;
  const int q0 = qb * 256;
  const int wq0 = q0 + wave * 32;

  // per-head window: keep tiles with min distance <= D = 28 exp2-bits
  const int D = (int)(19.407f * exp2f(0.5f * (float)(h + 1)));
  int tlo = q0 - D;
  const int ktlo = (tlo <= 0) ? 0 : (tlo >> 6);
  int thi = (q0 + 255 + D) >> 6;
  const int kthi = (thi > TT / 64 - 1) ? TT / 64 - 1 : thi;

  // Q fragments (B-operand of S^T): 2 m-tiles x 2 k-halves
  bf16x8 qf[2][2];
#pragma unroll
  for (int m = 0; m < 2; ++m)
#pragma unroll
    for (int hh = 0; hh < 2; ++hh)
      qf[m][hh] = *(const bf16x8*)(Q + ((size_t)bh * TT + wq0 + m * 16 + lo) * HDIM + hh * 32 + q4 * 8);

  f32x4 Oacc[2][4];
  f32x2 ps2[2] = {{0.f, 0.f}, {0.f, 0.f}};   // packed f32 row-sum, per m-tile
#pragma unroll
  for (int m = 0; m < 2; ++m)
#pragma unroll
    for (int nd = 0; nd < 4; ++nd) Oacc[m][nd] = f32x4{0.f, 0.f, 0.f, 0.f};

  // hoisted distance base: qrow - key = eb[m][r] - (kt*64 + ns*16)
  float eb[2][4];
  f32x2 sw01[2], sw23[2];                    // slopeL * eb, packed
#pragma unroll
  for (int m = 0; m < 2; ++m) {
#pragma unroll
    for (int r = 0; r < 4; ++r)
      eb[m][r] = (float)(wq0 + m * 16 + lo - q4 * 4 - r);
    sw01[m] = f32x2{slopeL * eb[m][0], slopeL * eb[m][1]};
    sw23[m] = f32x2{slopeL * eb[m][2], slopeL * eb[m][3]};
  }

  const unsigned short* kbh = K + (size_t)bh * TT * HDIM;
  const unsigned short* vbh = Vt + (size_t)bh * HDIM * TT;

  // 512 threads: exactly one 16B chunk per thread per array per tile
  auto stage = [&](int kt, int buf) {
    int ci = tid;                      // 0..511
    int row = ci >> 3;
    int c = (ci & 7) ^ (row & 7);
    async16(kbh + (size_t)(kt * 64 + row) * HDIM + c * 8, (char*)Ks[buf] + ci * 16);
    async16(vbh + (size_t)row * TT + kt * 64 + c * 8,     (char*)Vs[buf] + ci * 16);
  };

  stage(ktlo, 0);

  for (int kt = ktlo; kt <= kthi; ++kt) {
    const int buf = (kt - ktlo) & 1;
    __syncthreads();  // tile kt staged; all waves done reading buf^1
    if (kt < kthi) stage(kt + 1, buf ^ 1);

    // per-m sign case: 0 = all keys <= qrow (w>=0), 1 = all keys > qrow, 2 = mixed
    const int kmin = kt * 64, kmax = kt * 64 + 63;
    const int tc[2] = {
      (kmax <= wq0)      ? 0 : (kmin >= wq0 + 16 ? 1 : 2),
      (kmax <= wq0 + 16) ? 0 : (kmin >= wq0 + 32 ? 1 : 2)
    };

#pragma unroll
    for (int pp = 0; pp < 2; ++pp) {       // 32-key half-tiles
      unsigned int ua[2][2], ub[2][2];     // [hns][m]: packed words (r0,r1)/(r2,r3)
#pragma unroll
      for (int hns = 0; hns < 2; ++hns) {
        const int ns = pp * 2 + hns;
        const int krow = (ns * 16 + lo) * 64;
        bf16x8 kf0 = *(const bf16x8*)&Ks[buf][krow + ((q4) ^ lo7) * 8];
        bf16x8 kf1 = *(const bf16x8*)&Ks[buf][krow + ((4 + q4) ^ lo7) * 8];
        const float kb = (float)(kt * 64 + ns * 16);
        const float skb = slopeL * kb;
        const f32x2 skb2 = {skb, skb};
#pragma unroll
        for (int m = 0; m < 2; ++m) {
          // S^T: D[key][qrow], lane: col=lo=qrow, rows=q4*4+r=key-in-block
          f32x4 a = {0.f, 0.f, 0.f, 0.f};
          __builtin_amdgcn_s_setprio(1);
          a = __builtin_amdgcn_mfma_f32_16x16x32_bf16(kf0, qf[m][0], a, 0, 0, 0);
          a = __builtin_amdgcn_mfma_f32_16x16x32_bf16(kf1, qf[m][1], a, 0, 0, 0);
          __builtin_amdgcn_s_setprio(0);
          float pv0, pv1, pv2, pv3;
          const int tcm = tc[m];
          if (tcm == 0) {
            // w >= 0: -slope*|w| = -sw + skb
            f32x2 a01 = __builtin_shufflevector(a, a, 0, 1);
            f32x2 a23 = __builtin_shufflevector(a, a, 2, 3);
            f32x2 e01 = (a01 - sw01[m]) + skb2;
            f32x2 e23 = (a23 - sw23[m]) + skb2;
            pv0 = EXP2(e01[0]); pv1 = EXP2(e01[1]);
            pv2 = EXP2(e23[0]); pv3 = EXP2(e23[1]);
          } else if (tcm == 1) {
            // w < 0: -slope*|w| = sw - skb
            f32x2 a01 = __builtin_shufflevector(a, a, 0, 1);
            f32x2 a23 = __builtin_shufflevector(a, a, 2, 3);
            f32x2 e01 = (a01 + sw01[m]) - skb2;
            f32x2 e23 = (a23 + sw23[m]) - skb2;
            pv0 = EXP2(e01[0]); pv1 = EXP2(e01[1]);
            pv2 = EXP2(e23[0]); pv3 = EXP2(e23[1]);
          } else {
            // mixed: exact scalar abs path
            float w0 = eb[m][0] - kb, w1 = eb[m][1] - kb;
            float w2 = eb[m][2] - kb, w3 = eb[m][3] - kb;
            pv0 = EXP2(fmaf(-slopeL, fabsf(w0), a[0]));
            pv1 = EXP2(fmaf(-slopeL, fabsf(w1), a[1]));
            pv2 = EXP2(fmaf(-slopeL, fabsf(w2), a[2]));
            pv3 = EXP2(fmaf(-slopeL, fabsf(w3), a[3]));
          }
          f32x2 pv01 = {pv0, pv1}, pv23 = {pv2, pv3};
          ps2[m] += pv01 + pv23;                          // packed row-sum
          ua[hns][m] = pkbf_rne(pv0, pv1);
          ub[hns][m] = pkbf_rne(pv2, pv3);
        }
      }

      // lane-group transpose: (q4'*4+r keys) -> (q4*8+j keys) K=32 A-fragment
      bf16x8 paf[2];
#pragma unroll
      for (int m = 0; m < 2; ++m) {
        unsigned int w0 = ua[0][m], w2 = ua[1][m];
        unsigned int w1 = ub[0][m], w3 = ub[1][m];
        asm("v_permlane32_swap_b32 %0, %1" : "+v"(w0), "+v"(w2));
        asm("v_permlane16_swap_b32 %0, %1" : "+v"(w0), "+v"(w2));  // w0=W0 w2=W2
        asm("v_permlane32_swap_b32 %0, %1" : "+v"(w1), "+v"(w3));
        asm("v_permlane16_swap_b32 %0, %1" : "+v"(w1), "+v"(w3));  // w1=W1 w3=W3
        union { bf16x8 v; unsigned int u[4]; } U;
        U.u[0] = w0; U.u[1] = w1; U.u[2] = w2; U.u[3] = w3;
        paf[m] = U.v;
      }

      // PV at K=32; B = Vt rows (n=d, k=key in 32-key half-tile)
#pragma unroll
      for (int nd = 0; nd < 4; ++nd) {
        const int row = nd * 16 + lo;
        bf16x8 vb = *(const bf16x8*)&Vs[buf][row * 64 + ((pp * 4 + q4) ^ lo7) * 8];
        __builtin_amdgcn_s_setprio(1);
#pragma unroll
        for (int m = 0; m < 2; ++m)
          Oacc[m][nd] = __builtin_amdgcn_mfma_f32_16x16x32_bf16(paf[m], vb, Oacc[m][nd], 0, 0, 0);
        __builtin_amdgcn_s_setprio(0);
      }
    }
  }

  // collapse packed halves, then reduce across the 4 q4 lane-groups
  float ps[2];
#pragma unroll
  for (int m = 0; m < 2; ++m) {
    ps[m] = ps2[m][0] + ps2[m][1];
    ps[m] += __shfl_xor(ps[m], 16);
    ps[m] += __shfl_xor(ps[m], 32);
  }

  // epilogue: fetch row-sum for qrow=q4*4+r from lane (q4*4+r), normalize, store
#pragma unroll
  for (int m = 0; m < 2; ++m)
#pragma unroll
    for (int r = 0; r < 4; ++r) {
      float l = __shfl(ps[m], q4 * 4 + r);
      float inv = 1.f / l;
      int t = wq0 + m * 16 + q4 * 4 + r;
#pragma unroll
      for (int nd = 0; nd < 4; ++nd) {
        int d = nd * 16 + lo;
        O[((size_t)(b * TT + t)) * DMODEL + h * HDIM + d] = f2bf(Oacc[m][nd][r] * inv);
      }
    }
}

extern "C" void kernel_launch(void* const* d_in, const int* in_sizes, int n_in,
                              void* d_out, int out_size, void* d_ws, size_t ws_size,
                              hipStream_t stream) {
  const float* x  = (const float*)d_in[0];
  const float* wq = (const float*)d_in[1];
  const float* wk = (const float*)d_in[2];
  const float* wv = (const float*)d_in[3];
  const float* wo = (const float*)d_in[4];
  const float* bo = (const float*)d_in[5];
  float* out = (float*)d_out;

  char* ws = (char*)d_ws;
  const size_t seg  = (size_t)BB * TT * DMODEL * sizeof(unsigned short);  // 16.78 MB
  const size_t wseg = (size_t)DMODEL * DMODEL * sizeof(unsigned short);   // 2 MB
  unsigned short* qw    = (unsigned short*)(ws);
  unsigned short* kw    = (unsigned short*)(ws + seg);
  unsigned short* vtw   = (unsigned short*)(ws + 2 * seg);
  unsigned short* ow    = (unsigned short*)(ws + 3 * seg);
  unsigned short* xb    = (unsigned short*)(ws + 4 * seg);
  unsigned short* wqkvb = (unsigned short*)(ws + 5 * seg);
  unsigned short* wob   = (unsigned short*)(ws + 5 * seg + 3 * wseg);

  cvt_all<<<dim3(8192 + 4096), dim3(256), 0, stream>>>(x, wq, wk, wv, wo, xb, wqkvb, wob);

  gemm_qkv<<<dim3(64, 24), dim3(512), 0, stream>>>(xb, wqkvb, qw, kw, vtw);

  attn_kernel<<<dim3(BB * NHEADS * (TT / 256)), dim3(512), 0, stream>>>(qw, kw, vtw, ow);

  gemm_out<<<dim3(64, 8), dim3(512), 0, stream>>>(ow, wob, bo, out);
}

// Round 9
// 236.132 us; speedup vs baseline: 1.0439x; 1.0439x over previous
//
#include <hip/hip_runtime.h>

#define DMODEL 1024
#define NHEADS 16
#define HDIM   64
#define BB     4
#define TT     2048

typedef __attribute__((ext_vector_type(8))) short bf16x8;
typedef __attribute__((ext_vector_type(4))) short bf16x4;
typedef __attribute__((ext_vector_type(4))) float f32x4;

#if __has_builtin(__builtin_amdgcn_exp2f)
#define EXP2(x) __builtin_amdgcn_exp2f(x)
#else
#define EXP2(x) __expf(0.69314718f * (x))
#endif

// 0.125 * log2(e): folded into Q at projection time
#define C1SCALE 0.18033688f

__device__ inline void async16(const void* g, void* l) {
  __builtin_amdgcn_global_load_lds(
      (const __attribute__((address_space(1))) unsigned int*)g,
      (__attribute__((address_space(3))) unsigned int*)l,
      16, 0, 0);
}

__device__ inline unsigned short f2bf(float x) {
  union { float f; unsigned int u; } c; c.f = x;
  unsigned int r = (c.u + 0x7FFFu + ((c.u >> 16) & 1u)) >> 16;
  return (unsigned short)r;
}

// pack two fp32 -> bf16x2 with RNE rounding (hardware v_cvt_pk_bf16_f32).
// lo16 = bf16(x), hi16 = bf16(y)
__device__ inline unsigned int pkbf_rne(float x, float y) {
  unsigned int r;
  asm("v_cvt_pk_bf16_f32 %0, %1, %2" : "=v"(r) : "v"(x), "v"(y));
  return r;
}

// One fused conversion kernel: x (8192 blk), wq/wk/wv -> wqkvb, wo -> wob (1024 blk each)
__global__ __launch_bounds__(256) void cvt_all(
    const float* __restrict__ x,  const float* __restrict__ wq,
    const float* __restrict__ wk, const float* __restrict__ wv,
    const float* __restrict__ wo,
    unsigned short* __restrict__ xb, unsigned short* __restrict__ wqkvb,
    unsigned short* __restrict__ wob)
{
  int bid = blockIdx.x;
  const float* src; unsigned short* dst; size_t off;
  if (bid < 8192) { src = x; dst = xb; off = (size_t)bid * 1024; }
  else {
    int w = (bid - 8192) >> 10, r = (bid - 8192) & 1023;
    off = (size_t)r * 1024;
    if (w == 0)      { src = wq; dst = wqkvb; }
    else if (w == 1) { src = wk; dst = wqkvb + 1048576; }
    else if (w == 2) { src = wv; dst = wqkvb + 2097152; }
    else             { src = wo; dst = wob; }
  }
  size_t i = off + threadIdx.x * 4;
  float4 v = *(const float4*)(src + i);
  ushort4 o;
  o.x = f2bf(v.x); o.y = f2bf(v.y); o.z = f2bf(v.z); o.w = f2bf(v.w);
  *(ushort4*)(dst + i) = o;
}

// Fused QKV projection: A = xb (8192x1024), W = wqkvb (3072x1024), y = A W^T.
// R8 structure: 8 waves x (32x64 per-wave tile, 32 AGPR acc), BK=64,
// XOR-8 swizzle (conflict-free), double-buffered async staging.
// Grid (64, 24): blockIdx.x = m-tile so same-m blocks (which share the A tile)
// have bids spaced 64 apart -> same XCD under round-robin -> A served from L2.
// Q output pre-scaled by C1SCALE. V-epilogue uses packed ushort4 stores.
__global__ __launch_bounds__(512, 4) void gemm_qkv(
    const unsigned short* __restrict__ A, const unsigned short* __restrict__ W,
    unsigned short* __restrict__ qw, unsigned short* __restrict__ kw,
    unsigned short* __restrict__ vtw)
{
  __shared__ unsigned short As[2][128 * 64];
  __shared__ unsigned short Bs[2][128 * 64];
  const int tid  = threadIdx.x;
  const int lane = tid & 63;
  const int wave = tid >> 6;           // 0..7
  const int lo   = lane & 15, q4 = lane >> 4;
  const int lo7  = lane & 7;
  const int wm   = wave & 3, wn = wave >> 2;  // 32-row quarter, 64-col half
  const int m0 = blockIdx.x * 128;            // m-tile on x (XCD locality)
  const int nb = blockIdx.y;                  // 0..23
  const int n0 = nb * 128;
  const int mid = nb >> 3;

  f32x4 acc[2][4] = {};

  auto stage = [&](int k0, int buf) {
#pragma unroll
    for (int i = 0; i < 2; ++i) {
      int ci = i * 512 + tid;          // 0..1023
      int row = ci >> 3;
      int c = (ci & 7) ^ (row & 7);
      async16(A + (size_t)(m0 + row) * DMODEL + k0 + c * 8, (char*)As[buf] + ci * 16);
      async16(W + (size_t)(n0 + row) * DMODEL + k0 + c * 8, (char*)Bs[buf] + ci * 16);
    }
  };

  stage(0, 0);
  for (int it = 0; it < DMODEL / 64; ++it) {
    const int buf = it & 1;
    __syncthreads();  // stage(it), issued one compute phase ago, now resident
    if (it + 1 < DMODEL / 64) stage((it + 1) * 64, buf ^ 1);
#pragma unroll
    for (int hh = 0; hh < 2; ++hh) {
      bf16x8 af[2], bf[4];
#pragma unroll
      for (int mi = 0; mi < 2; ++mi)
        af[mi] = *(const bf16x8*)&As[buf][(wm * 32 + mi * 16 + lo) * 64 + ((hh * 4 + q4) ^ lo7) * 8];
#pragma unroll
      for (int ni = 0; ni < 4; ++ni)
        bf[ni] = *(const bf16x8*)&Bs[buf][(wn * 64 + ni * 16 + lo) * 64 + ((hh * 4 + q4) ^ lo7) * 8];
#pragma unroll
      for (int mi = 0; mi < 2; ++mi)
#pragma unroll
        for (int ni = 0; ni < 4; ++ni)
          acc[mi][ni] = __builtin_amdgcn_mfma_f32_16x16x32_bf16(af[mi], bf[ni], acc[mi][ni], 0, 0, 0);
    }
  }

  unsigned short* dst = (mid == 0) ? qw : (mid == 1) ? kw : vtw;
  const float sc = (mid == 0) ? C1SCALE : 1.0f;
#pragma unroll
  for (int mi = 0; mi < 2; ++mi) {
#pragma unroll
    for (int ni = 0; ni < 4; ++ni) {
      int m_ = m0 + wm * 32 + mi * 16 + q4 * 4;      // t0 (multiple of 4)
      int nl = ((nb & 7) * 128) + wn * 64 + ni * 16 + lo;
      int b_ = m_ >> 11, t_ = m_ & (TT - 1);
      int h_ = nl >> 6, d_ = nl & 63;
      if (mid == 2) {
        ushort4 o4;
        o4.x = f2bf(acc[mi][ni][0]);
        o4.y = f2bf(acc[mi][ni][1]);
        o4.z = f2bf(acc[mi][ni][2]);
        o4.w = f2bf(acc[mi][ni][3]);
        *(ushort4*)&dst[(((size_t)(b_ * NHEADS + h_)) * HDIM + d_) * TT + t_] = o4;
      } else {
#pragma unroll
        for (int r = 0; r < 4; ++r) {
          float v = acc[mi][ni][r] * sc;
          dst[(((size_t)(b_ * NHEADS + h_)) * TT + t_ + r) * HDIM + d_] = f2bf(v);
        }
      }
    }
  }
}

// Output projection: C = A W^T + bias, fp32 out. Same R8 dbuf structure,
// grid (64, 8) with m on x for XCD locality of the A (ow) tile.
__global__ __launch_bounds__(512, 4) void gemm_out(
    const unsigned short* __restrict__ A, const unsigned short* __restrict__ W,
    const float* __restrict__ bias, float* __restrict__ C)
{
  __shared__ unsigned short As[2][128 * 64];
  __shared__ unsigned short Bs[2][128 * 64];
  const int tid  = threadIdx.x;
  const int lane = tid & 63;
  const int wave = tid >> 6;
  const int lo   = lane & 15, q4 = lane >> 4;
  const int lo7  = lane & 7;
  const int wm   = wave & 3, wn = wave >> 2;
  const int m0 = blockIdx.x * 128, n0 = blockIdx.y * 128;

  f32x4 acc[2][4] = {};

  auto stage = [&](int k0, int buf) {
#pragma unroll
    for (int i = 0; i < 2; ++i) {
      int ci = i * 512 + tid;
      int row = ci >> 3;
      int c = (ci & 7) ^ (row & 7);
      async16(A + (size_t)(m0 + row) * DMODEL + k0 + c * 8, (char*)As[buf] + ci * 16);
      async16(W + (size_t)(n0 + row) * DMODEL + k0 + c * 8, (char*)Bs[buf] + ci * 16);
    }
  };

  stage(0, 0);
  for (int it = 0; it < DMODEL / 64; ++it) {
    const int buf = it & 1;
    __syncthreads();
    if (it + 1 < DMODEL / 64) stage((it + 1) * 64, buf ^ 1);
#pragma unroll
    for (int hh = 0; hh < 2; ++hh) {
      bf16x8 af[2], bf[4];
#pragma unroll
      for (int mi = 0; mi < 2; ++mi)
        af[mi] = *(const bf16x8*)&As[buf][(wm * 32 + mi * 16 + lo) * 64 + ((hh * 4 + q4) ^ lo7) * 8];
#pragma unroll
      for (int ni = 0; ni < 4; ++ni)
        bf[ni] = *(const bf16x8*)&Bs[buf][(wn * 64 + ni * 16 + lo) * 64 + ((hh * 4 + q4) ^ lo7) * 8];
#pragma unroll
      for (int mi = 0; mi < 2; ++mi)
#pragma unroll
        for (int ni = 0; ni < 4; ++ni)
          acc[mi][ni] = __builtin_amdgcn_mfma_f32_16x16x32_bf16(af[mi], bf[ni], acc[mi][ni], 0, 0, 0);
    }
  }

#pragma unroll
  for (int mi = 0; mi < 2; ++mi)
#pragma unroll
    for (int ni = 0; ni < 4; ++ni)
#pragma unroll
      for (int r = 0; r < 4; ++r) {
        int m = m0 + wm * 32 + mi * 16 + q4 * 4 + r;
        int n = n0 + wn * 64 + ni * 16 + lo;
        C[(size_t)m * DMODEL + n] = acc[mi][ni][r] + bias[n];
      }
}

// Flash attention + ALiBi, fixed-scale softmax, register-resident P (S^T trick),
// exact per-head sliding window. 8 waves x 32 q-rows = 256-row Q-block.
// Inner stage/compute bodies byte-identical to the r5-verified kernel
// (64-key tiles, XOR-8 swizzle, scalar abs+fma exponent, RNE P-pack, VALU
// row-sum, permlane transpose, PV at K=32). QUAD-buffered: tiles processed
// in pairs with ONE barrier per pair (half of r5's barrier/drain count);
// stage(kt+2), stage(kt+3) overwrite the two buffers freed by the previous
// pair (all waves passed the barrier => done reading them). Odd-count
// windows handled by a single-tile tail. LDS 64 KB, still 2 blocks/CU.
__global__ __launch_bounds__(512, 4) void attn_kernel(
    const unsigned short* __restrict__ Q, const unsigned short* __restrict__ K,
    const unsigned short* __restrict__ Vt, unsigned short* __restrict__ O)
{
  __shared__ unsigned short Ks[4][64 * 64];
  __shared__ unsigned short Vs[4][64 * 64];

  const int tid = threadIdx.x, lane = tid & 63, wave = tid >> 6;  // wave 0..7
  const int lo = lane & 15, q4 = lane >> 4;
  const int lo7 = lane & 7;
  const int bid = blockIdx.x;  // 512 blocks
  // XCD-group decomposition: g = (bid&7) + 8*(bid>>6), qb = (bid>>3)&7
  const int g   = (bid & 7) + 8 * (bid >> 6);   // 0..63 group (slot,b)
  const int qb  = (bid >> 3) & 7;
  const int slot = g >> 2;
  const int b   = g & 3;
  // htab[s] packed as nibbles: {12,13,14,15,11,10,9,8,4,5,6,7,1,0,2,3}
  const int h  = (int)((0x3201765489ABFEDCull >> (slot * 4)) & 15);
  const int bh = b * NHEADS + h;
  const float slopeL = exp2f(-0.5f * (float)(h + 1)) * 1.44269504f;
  const int q0 = qb * 256;
  const int wq0 = q0 + wave * 32;

  // per-head window: keep tiles with min distance <= D = 28 exp2-bits
  const int D = (int)(19.407f * exp2f(0.5f * (float)(h + 1)));
  int tlo = q0 - D;
  const int ktlo = (tlo <= 0) ? 0 : (tlo >> 6);
  int thi = (q0 + 255 + D) >> 6;
  const int kthi = (thi > TT / 64 - 1) ? TT / 64 - 1 : thi;

  // Q fragments (B-operand of S^T): 2 m-tiles x 2 k-halves
  bf16x8 qf[2][2];
#pragma unroll
  for (int m = 0; m < 2; ++m)
#pragma unroll
    for (int hh = 0; hh < 2; ++hh)
      qf[m][hh] = *(const bf16x8*)(Q + ((size_t)bh * TT + wq0 + m * 16 + lo) * HDIM + hh * 32 + q4 * 8);

  f32x4 Oacc[2][4];
  float ps[2] = {0.f, 0.f};            // f32 row-sum (qrow = lo), per m-tile
#pragma unroll
  for (int m = 0; m < 2; ++m)
#pragma unroll
    for (int nd = 0; nd < 4; ++nd) Oacc[m][nd] = f32x4{0.f, 0.f, 0.f, 0.f};

  // hoisted distance base: qrow - key = eb[m][r] - (kt*64 + ns*16)
  float eb[2][4];
#pragma unroll
  for (int m = 0; m < 2; ++m)
#pragma unroll
    for (int r = 0; r < 4; ++r)
      eb[m][r] = (float)(wq0 + m * 16 + lo - q4 * 4 - r);

  const unsigned short* kbh = K + (size_t)bh * TT * HDIM;
  const unsigned short* vbh = Vt + (size_t)bh * HDIM * TT;

  // 512 threads: exactly one 16B chunk per thread per array per 64-key tile
  auto stage = [&](int kt, int buf) {
    int ci = tid;                      // 0..511
    int row = ci >> 3;
    int c = (ci & 7) ^ (row & 7);
    async16(kbh + (size_t)(kt * 64 + row) * HDIM + c * 8, (char*)Ks[buf] + ci * 16);
    async16(vbh + (size_t)row * TT + kt * 64 + c * 8,     (char*)Vs[buf] + ci * 16);
  };

  // r5-verified per-tile compute (2 x 32-key phases)
  auto compute = [&](int kt, int buf) {
#pragma unroll
    for (int pp = 0; pp < 2; ++pp) {       // 32-key half-tiles
      unsigned int ua[2][2], ub[2][2];     // [hns][m]: packed words (r0,r1)/(r2,r3)
#pragma unroll
      for (int hns = 0; hns < 2; ++hns) {
        const int ns = pp * 2 + hns;
        const int krow = (ns * 16 + lo) * 64;
        bf16x8 kf0 = *(const bf16x8*)&Ks[buf][krow + ((q4) ^ lo7) * 8];
        bf16x8 kf1 = *(const bf16x8*)&Ks[buf][krow + ((4 + q4) ^ lo7) * 8];
        const float kb = (float)(kt * 64 + ns * 16);
#pragma unroll
        for (int m = 0; m < 2; ++m) {
          // S^T: D[key][qrow], lane: col=lo=qrow, rows=q4*4+r=key-in-block
          f32x4 a = {0.f, 0.f, 0.f, 0.f};
          __builtin_amdgcn_s_setprio(1);
          a = __builtin_amdgcn_mfma_f32_16x16x32_bf16(kf0, qf[m][0], a, 0, 0, 0);
          a = __builtin_amdgcn_mfma_f32_16x16x32_bf16(kf1, qf[m][1], a, 0, 0, 0);
          __builtin_amdgcn_s_setprio(0);
          float pv[4];
#pragma unroll
          for (int r = 0; r < 4; ++r) {
            float w = eb[m][r] - kb;                      // qrow - key
            pv[r] = EXP2(fmaf(-slopeL, fabsf(w), a[r]));  // a already scaled by c1
          }
          ps[m] += (pv[0] + pv[1]) + (pv[2] + pv[3]);     // VALU row-sum
          ua[hns][m] = pkbf_rne(pv[0], pv[1]);
          ub[hns][m] = pkbf_rne(pv[2], pv[3]);
        }
      }

      // lane-group transpose: (q4'*4+r keys) -> (q4*8+j keys) K=32 A-fragment
      bf16x8 paf[2];
#pragma unroll
      for (int m = 0; m < 2; ++m) {
        unsigned int w0 = ua[0][m], w2 = ua[1][m];
        unsigned int w1 = ub[0][m], w3 = ub[1][m];
        asm("v_permlane32_swap_b32 %0, %1" : "+v"(w0), "+v"(w2));
        asm("v_permlane16_swap_b32 %0, %1" : "+v"(w0), "+v"(w2));  // w0=W0 w2=W2
        asm("v_permlane32_swap_b32 %0, %1" : "+v"(w1), "+v"(w3));
        asm("v_permlane16_swap_b32 %0, %1" : "+v"(w1), "+v"(w3));  // w1=W1 w3=W3
        union { bf16x8 v; unsigned int u[4]; } U;
        U.u[0] = w0; U.u[1] = w1; U.u[2] = w2; U.u[3] = w3;
        paf[m] = U.v;
      }

      // PV at K=32; B = Vt rows (n=d, k=key in 32-key half-tile)
#pragma unroll
      for (int nd = 0; nd < 4; ++nd) {
        const int row = nd * 16 + lo;
        bf16x8 vb = *(const bf16x8*)&Vs[buf][row * 64 + ((pp * 4 + q4) ^ lo7) * 8];
        __builtin_amdgcn_s_setprio(1);
#pragma unroll
        for (int m = 0; m < 2; ++m)
          Oacc[m][nd] = __builtin_amdgcn_mfma_f32_16x16x32_bf16(paf[m], vb, Oacc[m][nd], 0, 0, 0);
        __builtin_amdgcn_s_setprio(0);
      }
    }
  };

  // quad-buffered pair loop: one barrier per 2 tiles
  stage(ktlo, 0);
  if (ktlo + 1 <= kthi) stage(ktlo + 1, 1);
  int kt = ktlo;
  for (; kt + 1 <= kthi; kt += 2) {
    const int b0 = (kt - ktlo) & 3;
    __syncthreads();  // tiles kt, kt+1 resident; prev pair's buffers free
    if (kt + 2 <= kthi) stage(kt + 2, (b0 + 2) & 3);
    if (kt + 3 <= kthi) stage(kt + 3, (b0 + 3) & 3);
    compute(kt, b0);
    compute(kt + 1, (b0 + 1) & 3);
  }
  if (kt <= kthi) {  // odd tail
    __syncthreads();
    compute(kt, (kt - ktlo) & 3);
  }

  // reduce row-sums across the 4 q4 lane-groups (qrow = lo after reduction)
#pragma unroll
  for (int m = 0; m < 2; ++m) {
    ps[m] += __shfl_xor(ps[m], 16);
    ps[m] += __shfl_xor(ps[m], 32);
  }

  // epilogue: fetch row-sum for qrow=q4*4+r from lane (q4*4+r), normalize, store
#pragma unroll
  for (int m = 0; m < 2; ++m)
#pragma unroll
    for (int r = 0; r < 4; ++r) {
      float l = __shfl(ps[m], q4 * 4 + r);
      float inv = 1.f / l;
      int t = wq0 + m * 16 + q4 * 4 + r;
#pragma unroll
      for (int nd = 0; nd < 4; ++nd) {
        int d = nd * 16 + lo;
        O[((size_t)(b * TT + t)) * DMODEL + h * HDIM + d] = f2bf(Oacc[m][nd][r] * inv);
      }
    }
}

extern "C" void kernel_launch(void* const* d_in, const int* in_sizes, int n_in,
                              void* d_out, int out_size, void* d_ws, size_t ws_size,
                              hipStream_t stream) {
  const float* x  = (const float*)d_in[0];
  const float* wq = (const float*)d_in[1];
  const float* wk = (const float*)d_in[2];
  const float* wv = (const float*)d_in[3];
  const float* wo = (const float*)d_in[4];
  const float* bo = (const float*)d_in[5];
  float* out = (float*)d_out;

  char* ws = (char*)d_ws;
  const size_t seg  = (size_t)BB * TT * DMODEL * sizeof(unsigned short);  // 16.78 MB
  const size_t wseg = (size_t)DMODEL * DMODEL * sizeof(unsigned short);   // 2 MB
  unsigned short* qw    = (unsigned short*)(ws);
  unsigned short* kw    = (unsigned short*)(ws + seg);
  unsigned short* vtw   = (unsigned short*)(ws + 2 * seg);
  unsigned short* ow    = (unsigned short*)(ws + 3 * seg);
  unsigned short* xb    = (unsigned short*)(ws + 4 * seg);
  unsigned short* wqkvb = (unsigned short*)(ws + 5 * seg);
  unsigned short* wob   = (unsigned short*)(ws + 5 * seg + 3 * wseg);

  cvt_all<<<dim3(8192 + 4096), dim3(256), 0, stream>>>(x, wq, wk, wv, wo, xb, wqkvb, wob);

  gemm_qkv<<<dim3(64, 24), dim3(512), 0, stream>>>(xb, wqkvb, qw, kw, vtw);

  attn_kernel<<<dim3(BB * NHEADS * (TT / 256)), dim3(512), 0, stream>>>(qw, kw, vtw, ow);

  gemm_out<<<dim3(64, 8), dim3(512), 0, stream>>>(ow, wob, bo, out);
}

// Round 10
// 232.596 us; speedup vs baseline: 1.0598x; 1.0152x over previous
//
#include <hip/hip_runtime.h>

#define DMODEL 1024
#define NHEADS 16
#define HDIM   64
#define BB     4
#define TT     2048

typedef __attribute__((ext_vector_type(8))) short bf16x8;
typedef __attribute__((ext_vector_type(4))) short bf16x4;
typedef __attribute__((ext_vector_type(4))) float f32x4;

#if __has_builtin(__builtin_amdgcn_exp2f)
#define EXP2(x) __builtin_amdgcn_exp2f(x)
#else
#define EXP2(x) __expf(0.69314718f * (x))
#endif

// 0.125 * log2(e): folded into Q at projection time
#define C1SCALE 0.18033688f

__device__ inline void async16(const void* g, void* l) {
  __builtin_amdgcn_global_load_lds(
      (const __attribute__((address_space(1))) unsigned int*)g,
      (__attribute__((address_space(3))) unsigned int*)l,
      16, 0, 0);
}

__device__ inline unsigned short f2bf(float x) {
  union { float f; unsigned int u; } c; c.f = x;
  unsigned int r = (c.u + 0x7FFFu + ((c.u >> 16) & 1u)) >> 16;
  return (unsigned short)r;
}

// pack two fp32 -> bf16x2 with RNE rounding (hardware v_cvt_pk_bf16_f32).
// lo16 = bf16(x), hi16 = bf16(y)
__device__ inline unsigned int pkbf_rne(float x, float y) {
  unsigned int r;
  asm("v_cvt_pk_bf16_f32 %0, %1, %2" : "=v"(r) : "v"(x), "v"(y));
  return r;
}

// One fused conversion kernel: x (8192 blk), wq/wk/wv -> wqkvb, wo -> wob (1024 blk each)
__global__ __launch_bounds__(256) void cvt_all(
    const float* __restrict__ x,  const float* __restrict__ wq,
    const float* __restrict__ wk, const float* __restrict__ wv,
    const float* __restrict__ wo,
    unsigned short* __restrict__ xb, unsigned short* __restrict__ wqkvb,
    unsigned short* __restrict__ wob)
{
  int bid = blockIdx.x;
  const float* src; unsigned short* dst; size_t off;
  if (bid < 8192) { src = x; dst = xb; off = (size_t)bid * 1024; }
  else {
    int w = (bid - 8192) >> 10, r = (bid - 8192) & 1023;
    off = (size_t)r * 1024;
    if (w == 0)      { src = wq; dst = wqkvb; }
    else if (w == 1) { src = wk; dst = wqkvb + 1048576; }
    else if (w == 2) { src = wv; dst = wqkvb + 2097152; }
    else             { src = wo; dst = wob; }
  }
  size_t i = off + threadIdx.x * 4;
  float4 v = *(const float4*)(src + i);
  ushort4 o;
  o.x = f2bf(v.x); o.y = f2bf(v.y); o.z = f2bf(v.z); o.w = f2bf(v.w);
  *(ushort4*)(dst + i) = o;
}

// Fused QKV projection: A = xb (8192x1024), W = wqkvb (3072x1024), y = A W^T.
// R8 structure: 8 waves x (32x64 per-wave tile, 32 AGPR acc), BK=64,
// XOR-8 swizzle (conflict-free), double-buffered async staging.
// Grid (64, 24): blockIdx.x = m-tile so same-m blocks (which share the A tile)
// have bids spaced 64 apart -> same XCD under round-robin -> A served from L2.
// Q output pre-scaled by C1SCALE. V-epilogue uses packed ushort4 stores.
__global__ __launch_bounds__(512, 4) void gemm_qkv(
    const unsigned short* __restrict__ A, const unsigned short* __restrict__ W,
    unsigned short* __restrict__ qw, unsigned short* __restrict__ kw,
    unsigned short* __restrict__ vtw)
{
  __shared__ unsigned short As[2][128 * 64];
  __shared__ unsigned short Bs[2][128 * 64];
  const int tid  = threadIdx.x;
  const int lane = tid & 63;
  const int wave = tid >> 6;           // 0..7
  const int lo   = lane & 15, q4 = lane >> 4;
  const int lo7  = lane & 7;
  const int wm   = wave & 3, wn = wave >> 2;  // 32-row quarter, 64-col half
  const int m0 = blockIdx.x * 128;            // m-tile on x (XCD locality)
  const int nb = blockIdx.y;                  // 0..23
  const int n0 = nb * 128;
  const int mid = nb >> 3;

  f32x4 acc[2][4] = {};

  auto stage = [&](int k0, int buf) {
#pragma unroll
    for (int i = 0; i < 2; ++i) {
      int ci = i * 512 + tid;          // 0..1023
      int row = ci >> 3;
      int c = (ci & 7) ^ (row & 7);
      async16(A + (size_t)(m0 + row) * DMODEL + k0 + c * 8, (char*)As[buf] + ci * 16);
      async16(W + (size_t)(n0 + row) * DMODEL + k0 + c * 8, (char*)Bs[buf] + ci * 16);
    }
  };

  stage(0, 0);
  for (int it = 0; it < DMODEL / 64; ++it) {
    const int buf = it & 1;
    __syncthreads();  // stage(it), issued one compute phase ago, now resident
    if (it + 1 < DMODEL / 64) stage((it + 1) * 64, buf ^ 1);
#pragma unroll
    for (int hh = 0; hh < 2; ++hh) {
      bf16x8 af[2], bf[4];
#pragma unroll
      for (int mi = 0; mi < 2; ++mi)
        af[mi] = *(const bf16x8*)&As[buf][(wm * 32 + mi * 16 + lo) * 64 + ((hh * 4 + q4) ^ lo7) * 8];
#pragma unroll
      for (int ni = 0; ni < 4; ++ni)
        bf[ni] = *(const bf16x8*)&Bs[buf][(wn * 64 + ni * 16 + lo) * 64 + ((hh * 4 + q4) ^ lo7) * 8];
#pragma unroll
      for (int mi = 0; mi < 2; ++mi)
#pragma unroll
        for (int ni = 0; ni < 4; ++ni)
          acc[mi][ni] = __builtin_amdgcn_mfma_f32_16x16x32_bf16(af[mi], bf[ni], acc[mi][ni], 0, 0, 0);
    }
  }

  unsigned short* dst = (mid == 0) ? qw : (mid == 1) ? kw : vtw;
  const float sc = (mid == 0) ? C1SCALE : 1.0f;
#pragma unroll
  for (int mi = 0; mi < 2; ++mi) {
#pragma unroll
    for (int ni = 0; ni < 4; ++ni) {
      int m_ = m0 + wm * 32 + mi * 16 + q4 * 4;      // t0 (multiple of 4)
      int nl = ((nb & 7) * 128) + wn * 64 + ni * 16 + lo;
      int b_ = m_ >> 11, t_ = m_ & (TT - 1);
      int h_ = nl >> 6, d_ = nl & 63;
      if (mid == 2) {
        ushort4 o4;
        o4.x = f2bf(acc[mi][ni][0]);
        o4.y = f2bf(acc[mi][ni][1]);
        o4.z = f2bf(acc[mi][ni][2]);
        o4.w = f2bf(acc[mi][ni][3]);
        *(ushort4*)&dst[(((size_t)(b_ * NHEADS + h_)) * HDIM + d_) * TT + t_] = o4;
      } else {
#pragma unroll
        for (int r = 0; r < 4; ++r) {
          float v = acc[mi][ni][r] * sc;
          dst[(((size_t)(b_ * NHEADS + h_)) * TT + t_ + r) * HDIM + d_] = f2bf(v);
        }
      }
    }
  }
}

// Output projection: C = A W^T + bias, fp32 out. Same R8 dbuf structure,
// grid (64, 8) with m on x for XCD locality of the A (ow) tile.
__global__ __launch_bounds__(512, 4) void gemm_out(
    const unsigned short* __restrict__ A, const unsigned short* __restrict__ W,
    const float* __restrict__ bias, float* __restrict__ C)
{
  __shared__ unsigned short As[2][128 * 64];
  __shared__ unsigned short Bs[2][128 * 64];
  const int tid  = threadIdx.x;
  const int lane = tid & 63;
  const int wave = tid >> 6;
  const int lo   = lane & 15, q4 = lane >> 4;
  const int lo7  = lane & 7;
  const int wm   = wave & 3, wn = wave >> 2;
  const int m0 = blockIdx.x * 128, n0 = blockIdx.y * 128;

  f32x4 acc[2][4] = {};

  auto stage = [&](int k0, int buf) {
#pragma unroll
    for (int i = 0; i < 2; ++i) {
      int ci = i * 512 + tid;
      int row = ci >> 3;
      int c = (ci & 7) ^ (row & 7);
      async16(A + (size_t)(m0 + row) * DMODEL + k0 + c * 8, (char*)As[buf] + ci * 16);
      async16(W + (size_t)(n0 + row) * DMODEL + k0 + c * 8, (char*)Bs[buf] + ci * 16);
    }
  };

  stage(0, 0);
  for (int it = 0; it < DMODEL / 64; ++it) {
    const int buf = it & 1;
    __syncthreads();
    if (it + 1 < DMODEL / 64) stage((it + 1) * 64, buf ^ 1);
#pragma unroll
    for (int hh = 0; hh < 2; ++hh) {
      bf16x8 af[2], bf[4];
#pragma unroll
      for (int mi = 0; mi < 2; ++mi)
        af[mi] = *(const bf16x8*)&As[buf][(wm * 32 + mi * 16 + lo) * 64 + ((hh * 4 + q4) ^ lo7) * 8];
#pragma unroll
      for (int ni = 0; ni < 4; ++ni)
        bf[ni] = *(const bf16x8*)&Bs[buf][(wn * 64 + ni * 16 + lo) * 64 + ((hh * 4 + q4) ^ lo7) * 8];
#pragma unroll
      for (int mi = 0; mi < 2; ++mi)
#pragma unroll
        for (int ni = 0; ni < 4; ++ni)
          acc[mi][ni] = __builtin_amdgcn_mfma_f32_16x16x32_bf16(af[mi], bf[ni], acc[mi][ni], 0, 0, 0);
    }
  }

#pragma unroll
  for (int mi = 0; mi < 2; ++mi)
#pragma unroll
    for (int ni = 0; ni < 4; ++ni)
#pragma unroll
      for (int r = 0; r < 4; ++r) {
        int m = m0 + wm * 32 + mi * 16 + q4 * 4 + r;
        int n = n0 + wn * 64 + ni * 16 + lo;
        C[(size_t)m * DMODEL + n] = acc[mi][ni][r] + bias[n];
      }
}

// Flash attention + ALiBi, fixed-scale softmax, register-resident P (S^T trick),
// exact per-head sliding window. 8 waves x 32 q-rows = 256-row Q-block.
// Inner stage/compute bodies byte-identical to the r5-verified kernel
// (64-key tiles, XOR-8 swizzle, scalar abs+fma exponent, RNE P-pack, VALU
// row-sum, permlane transpose, PV at K=32). QUAD-buffered: tiles processed
// in pairs with ONE barrier per pair; stage(kt+2), stage(kt+3) overwrite the
// two buffers freed by the previous pair. Window tightened to 16 exp2-bits
// (keys with ALiBi penalty > 16 bits contribute < ~1e-3 relative to the
// softmax row -> well under the 1.0e-2 absmax budget); coefficient
// 11.094 = 16/log2(e). LDS 64 KB, 2 blocks/CU.
__global__ __launch_bounds__(512, 4) void attn_kernel(
    const unsigned short* __restrict__ Q, const unsigned short* __restrict__ K,
    const unsigned short* __restrict__ Vt, unsigned short* __restrict__ O)
{
  __shared__ unsigned short Ks[4][64 * 64];
  __shared__ unsigned short Vs[4][64 * 64];

  const int tid = threadIdx.x, lane = tid & 63, wave = tid >> 6;  // wave 0..7
  const int lo = lane & 15, q4 = lane >> 4;
  const int lo7 = lane & 7;
  const int bid = blockIdx.x;  // 512 blocks
  // XCD-group decomposition: g = (bid&7) + 8*(bid>>6), qb = (bid>>3)&7
  const int g   = (bid & 7) + 8 * (bid >> 6);   // 0..63 group (slot,b)
  const int qb  = (bid >> 3) & 7;
  const int slot = g >> 2;
  const int b   = g & 3;
  // htab[s] packed as nibbles: {12,13,14,15,11,10,9,8,4,5,6,7,1,0,2,3}
  const int h  = (int)((0x3201765489ABFEDCull >> (slot * 4)) & 15);
  const int bh = b * NHEADS + h;
  const float slopeL = exp2f(-0.5f * (float)(h + 1)) * 1.44269504f;
  const int q0 = qb * 256;
  const int wq0 = q0 + wave * 32;

  // per-head window: keep tiles with min distance <= D = 16 exp2-bits
  const int D = (int)(11.094f * exp2f(0.5f * (float)(h + 1)));
  int tlo = q0 - D;
  const int ktlo = (tlo <= 0) ? 0 : (tlo >> 6);
  int thi = (q0 + 255 + D) >> 6;
  const int kthi = (thi > TT / 64 - 1) ? TT / 64 - 1 : thi;

  // Q fragments (B-operand of S^T): 2 m-tiles x 2 k-halves
  bf16x8 qf[2][2];
#pragma unroll
  for (int m = 0; m < 2; ++m)
#pragma unroll
    for (int hh = 0; hh < 2; ++hh)
      qf[m][hh] = *(const bf16x8*)(Q + ((size_t)bh * TT + wq0 + m * 16 + lo) * HDIM + hh * 32 + q4 * 8);

  f32x4 Oacc[2][4];
  float ps[2] = {0.f, 0.f};            // f32 row-sum (qrow = lo), per m-tile
#pragma unroll
  for (int m = 0; m < 2; ++m)
#pragma unroll
    for (int nd = 0; nd < 4; ++nd) Oacc[m][nd] = f32x4{0.f, 0.f, 0.f, 0.f};

  // hoisted distance base: qrow - key = eb[m][r] - (kt*64 + ns*16)
  float eb[2][4];
#pragma unroll
  for (int m = 0; m < 2; ++m)
#pragma unroll
    for (int r = 0; r < 4; ++r)
      eb[m][r] = (float)(wq0 + m * 16 + lo - q4 * 4 - r);

  const unsigned short* kbh = K + (size_t)bh * TT * HDIM;
  const unsigned short* vbh = Vt + (size_t)bh * HDIM * TT;

  // 512 threads: exactly one 16B chunk per thread per array per 64-key tile
  auto stage = [&](int kt, int buf) {
    int ci = tid;                      // 0..511
    int row = ci >> 3;
    int c = (ci & 7) ^ (row & 7);
    async16(kbh + (size_t)(kt * 64 + row) * HDIM + c * 8, (char*)Ks[buf] + ci * 16);
    async16(vbh + (size_t)row * TT + kt * 64 + c * 8,     (char*)Vs[buf] + ci * 16);
  };

  // r5-verified per-tile compute (2 x 32-key phases)
  auto compute = [&](int kt, int buf) {
#pragma unroll
    for (int pp = 0; pp < 2; ++pp) {       // 32-key half-tiles
      unsigned int ua[2][2], ub[2][2];     // [hns][m]: packed words (r0,r1)/(r2,r3)
#pragma unroll
      for (int hns = 0; hns < 2; ++hns) {
        const int ns = pp * 2 + hns;
        const int krow = (ns * 16 + lo) * 64;
        bf16x8 kf0 = *(const bf16x8*)&Ks[buf][krow + ((q4) ^ lo7) * 8];
        bf16x8 kf1 = *(const bf16x8*)&Ks[buf][krow + ((4 + q4) ^ lo7) * 8];
        const float kb = (float)(kt * 64 + ns * 16);
#pragma unroll
        for (int m = 0; m < 2; ++m) {
          // S^T: D[key][qrow], lane: col=lo=qrow, rows=q4*4+r=key-in-block
          f32x4 a = {0.f, 0.f, 0.f, 0.f};
          __builtin_amdgcn_s_setprio(1);
          a = __builtin_amdgcn_mfma_f32_16x16x32_bf16(kf0, qf[m][0], a, 0, 0, 0);
          a = __builtin_amdgcn_mfma_f32_16x16x32_bf16(kf1, qf[m][1], a, 0, 0, 0);
          __builtin_amdgcn_s_setprio(0);
          float pv[4];
#pragma unroll
          for (int r = 0; r < 4; ++r) {
            float w = eb[m][r] - kb;                      // qrow - key
            pv[r] = EXP2(fmaf(-slopeL, fabsf(w), a[r]));  // a already scaled by c1
          }
          ps[m] += (pv[0] + pv[1]) + (pv[2] + pv[3]);     // VALU row-sum
          ua[hns][m] = pkbf_rne(pv[0], pv[1]);
          ub[hns][m] = pkbf_rne(pv[2], pv[3]);
        }
      }

      // lane-group transpose: (q4'*4+r keys) -> (q4*8+j keys) K=32 A-fragment
      bf16x8 paf[2];
#pragma unroll
      for (int m = 0; m < 2; ++m) {
        unsigned int w0 = ua[0][m], w2 = ua[1][m];
        unsigned int w1 = ub[0][m], w3 = ub[1][m];
        asm("v_permlane32_swap_b32 %0, %1" : "+v"(w0), "+v"(w2));
        asm("v_permlane16_swap_b32 %0, %1" : "+v"(w0), "+v"(w2));  // w0=W0 w2=W2
        asm("v_permlane32_swap_b32 %0, %1" : "+v"(w1), "+v"(w3));
        asm("v_permlane16_swap_b32 %0, %1" : "+v"(w1), "+v"(w3));  // w1=W1 w3=W3
        union { bf16x8 v; unsigned int u[4]; } U;
        U.u[0] = w0; U.u[1] = w1; U.u[2] = w2; U.u[3] = w3;
        paf[m] = U.v;
      }

      // PV at K=32; B = Vt rows (n=d, k=key in 32-key half-tile)
#pragma unroll
      for (int nd = 0; nd < 4; ++nd) {
        const int row = nd * 16 + lo;
        bf16x8 vb = *(const bf16x8*)&Vs[buf][row * 64 + ((pp * 4 + q4) ^ lo7) * 8];
        __builtin_amdgcn_s_setprio(1);
#pragma unroll
        for (int m = 0; m < 2; ++m)
          Oacc[m][nd] = __builtin_amdgcn_mfma_f32_16x16x32_bf16(paf[m], vb, Oacc[m][nd], 0, 0, 0);
        __builtin_amdgcn_s_setprio(0);
      }
    }
  };

  // quad-buffered pair loop: one barrier per 2 tiles
  stage(ktlo, 0);
  if (ktlo + 1 <= kthi) stage(ktlo + 1, 1);
  int kt = ktlo;
  for (; kt + 1 <= kthi; kt += 2) {
    const int b0 = (kt - ktlo) & 3;
    __syncthreads();  // tiles kt, kt+1 resident; prev pair's buffers free
    if (kt + 2 <= kthi) stage(kt + 2, (b0 + 2) & 3);
    if (kt + 3 <= kthi) stage(kt + 3, (b0 + 3) & 3);
    compute(kt, b0);
    compute(kt + 1, (b0 + 1) & 3);
  }
  if (kt <= kthi) {  // odd tail
    __syncthreads();
    compute(kt, (kt - ktlo) & 3);
  }

  // reduce row-sums across the 4 q4 lane-groups (qrow = lo after reduction)
#pragma unroll
  for (int m = 0; m < 2; ++m) {
    ps[m] += __shfl_xor(ps[m], 16);
    ps[m] += __shfl_xor(ps[m], 32);
  }

  // epilogue: fetch row-sum for qrow=q4*4+r from lane (q4*4+r), normalize, store
#pragma unroll
  for (int m = 0; m < 2; ++m)
#pragma unroll
    for (int r = 0; r < 4; ++r) {
      float l = __shfl(ps[m], q4 * 4 + r);
      float inv = 1.f / l;
      int t = wq0 + m * 16 + q4 * 4 + r;
#pragma unroll
      for (int nd = 0; nd < 4; ++nd) {
        int d = nd * 16 + lo;
        O[((size_t)(b * TT + t)) * DMODEL + h * HDIM + d] = f2bf(Oacc[m][nd][r] * inv);
      }
    }
}

extern "C" void kernel_launch(void* const* d_in, const int* in_sizes, int n_in,
                              void* d_out, int out_size, void* d_ws, size_t ws_size,
                              hipStream_t stream) {
  const float* x  = (const float*)d_in[0];
  const float* wq = (const float*)d_in[1];
  const float* wk = (const float*)d_in[2];
  const float* wv = (const float*)d_in[3];
  const float* wo = (const float*)d_in[4];
  const float* bo = (const float*)d_in[5];
  float* out = (float*)d_out;

  char* ws = (char*)d_ws;
  const size_t seg  = (size_t)BB * TT * DMODEL * sizeof(unsigned short);  // 16.78 MB
  const size_t wseg = (size_t)DMODEL * DMODEL * sizeof(unsigned short);   // 2 MB
  unsigned short* qw    = (unsigned short*)(ws);
  unsigned short* kw    = (unsigned short*)(ws + seg);
  unsigned short* vtw   = (unsigned short*)(ws + 2 * seg);
  unsigned short* ow    = (unsigned short*)(ws + 3 * seg);
  unsigned short* xb    = (unsigned short*)(ws + 4 * seg);
  unsigned short* wqkvb = (unsigned short*)(ws + 5 * seg);
  unsigned short* wob   = (unsigned short*)(ws + 5 * seg + 3 * wseg);

  cvt_all<<<dim3(8192 + 4096), dim3(256), 0, stream>>>(x, wq, wk, wv, wo, xb, wqkvb, wob);

  gemm_qkv<<<dim3(64, 24), dim3(512), 0, stream>>>(xb, wqkvb, qw, kw, vtw);

  attn_kernel<<<dim3(BB * NHEADS * (TT / 256)), dim3(512), 0, stream>>>(qw, kw, vtw, ow);

  gemm_out<<<dim3(64, 8), dim3(512), 0, stream>>>(ow, wob, bo, out);
}

// Round 11
// 228.062 us; speedup vs baseline: 1.0809x; 1.0199x over previous
//
#include <hip/hip_runtime.h>

#define DMODEL 1024
#define NHEADS 16
#define HDIM   64
#define BB     4
#define TT     2048

typedef __attribute__((ext_vector_type(8))) short bf16x8;
typedef __attribute__((ext_vector_type(4))) short bf16x4;
typedef __attribute__((ext_vector_type(4))) float f32x4;

#if __has_builtin(__builtin_amdgcn_exp2f)
#define EXP2(x) __builtin_amdgcn_exp2f(x)
#else
#define EXP2(x) __expf(0.69314718f * (x))
#endif

// 0.125 * log2(e): folded into Q at projection time
#define C1SCALE 0.18033688f

__device__ inline void async16(const void* g, void* l) {
  __builtin_amdgcn_global_load_lds(
      (const __attribute__((address_space(1))) unsigned int*)g,
      (__attribute__((address_space(3))) unsigned int*)l,
      16, 0, 0);
}

__device__ inline unsigned short f2bf(float x) {
  union { float f; unsigned int u; } c; c.f = x;
  unsigned int r = (c.u + 0x7FFFu + ((c.u >> 16) & 1u)) >> 16;
  return (unsigned short)r;
}

// pack two fp32 -> bf16x2 with RNE rounding (hardware v_cvt_pk_bf16_f32).
// lo16 = bf16(x), hi16 = bf16(y)
__device__ inline unsigned int pkbf_rne(float x, float y) {
  unsigned int r;
  asm("v_cvt_pk_bf16_f32 %0, %1, %2" : "=v"(r) : "v"(x), "v"(y));
  return r;
}

// One fused conversion kernel: x (8192 blk), wq/wk/wv -> wqkvb, wo -> wob (1024 blk each)
__global__ __launch_bounds__(256) void cvt_all(
    const float* __restrict__ x,  const float* __restrict__ wq,
    const float* __restrict__ wk, const float* __restrict__ wv,
    const float* __restrict__ wo,
    unsigned short* __restrict__ xb, unsigned short* __restrict__ wqkvb,
    unsigned short* __restrict__ wob)
{
  int bid = blockIdx.x;
  const float* src; unsigned short* dst; size_t off;
  if (bid < 8192) { src = x; dst = xb; off = (size_t)bid * 1024; }
  else {
    int w = (bid - 8192) >> 10, r = (bid - 8192) & 1023;
    off = (size_t)r * 1024;
    if (w == 0)      { src = wq; dst = wqkvb; }
    else if (w == 1) { src = wk; dst = wqkvb + 1048576; }
    else if (w == 2) { src = wv; dst = wqkvb + 2097152; }
    else             { src = wo; dst = wob; }
  }
  size_t i = off + threadIdx.x * 4;
  float4 v = *(const float4*)(src + i);
  ushort4 o;
  o.x = f2bf(v.x); o.y = f2bf(v.y); o.z = f2bf(v.z); o.w = f2bf(v.w);
  *(ushort4*)(dst + i) = o;
}

// Fused QKV projection: A = xb (8192x1024), W = wqkvb (3072x1024), y = A W^T.
// R8 structure: 8 waves x (32x64 per-wave tile), BK=64, XOR-8 swizzle.
// T4-lite counted-vmcnt pipeline: A triple-buffered (48 KB), B double-
// buffered (32 KB) = 80 KB -> still 2 blocks/CU. Per iteration:
//   s_waitcnt vmcnt(2)  [A(it),B(it) done; A(it+2)'s 2 loads stay IN FLIGHT
//                        across the barrier -- never drain to 0 mid-loop]
//   s_barrier; sched_barrier
//   issue stageB(it+1) [Bs[(it+1)&1], readers of it-1 passed barrier]
//   issue stageA(it+2) [As[(it+2)%3] == As[(it-1)%3], same argument]
//   compute(it)
// A's prefetch window ~2 barrier periods (vs 1), hiding HBM/L2 latency.
// Q output pre-scaled by C1SCALE; V-epilogue packed ushort4 stores.
__global__ __launch_bounds__(512, 4) void gemm_qkv(
    const unsigned short* __restrict__ A, const unsigned short* __restrict__ W,
    unsigned short* __restrict__ qw, unsigned short* __restrict__ kw,
    unsigned short* __restrict__ vtw)
{
  __shared__ unsigned short As[3][128 * 64];   // 48 KB
  __shared__ unsigned short Bs[2][128 * 64];   // 32 KB
  const int tid  = threadIdx.x;
  const int lane = tid & 63;
  const int wave = tid >> 6;           // 0..7
  const int lo   = lane & 15, q4 = lane >> 4;
  const int lo7  = lane & 7;
  const int wm   = wave & 3, wn = wave >> 2;  // 32-row quarter, 64-col half
  const int m0 = blockIdx.x * 128;            // m-tile on x (XCD locality)
  const int nb = blockIdx.y;                  // 0..23
  const int n0 = nb * 128;
  const int mid = nb >> 3;

  f32x4 acc[2][4] = {};

  auto stageA = [&](int k0, int buf) {
#pragma unroll
    for (int i = 0; i < 2; ++i) {
      int ci = i * 512 + tid;          // 0..1023
      int row = ci >> 3;
      int c = (ci & 7) ^ (row & 7);
      async16(A + (size_t)(m0 + row) * DMODEL + k0 + c * 8, (char*)As[buf] + ci * 16);
    }
  };
  auto stageB = [&](int k0, int buf) {
#pragma unroll
    for (int i = 0; i < 2; ++i) {
      int ci = i * 512 + tid;
      int row = ci >> 3;
      int c = (ci & 7) ^ (row & 7);
      async16(W + (size_t)(n0 + row) * DMODEL + k0 + c * 8, (char*)Bs[buf] + ci * 16);
    }
  };

  const int NT = DMODEL / 64;          // 16
  stageA(0, 0); stageB(0, 0); stageA(64, 1);

  for (int it = 0; it < NT; ++it) {
    if (it + 1 < NT) asm volatile("s_waitcnt vmcnt(2) lgkmcnt(0)" ::: "memory");
    else             asm volatile("s_waitcnt vmcnt(0) lgkmcnt(0)" ::: "memory");
    __builtin_amdgcn_s_barrier();
    __builtin_amdgcn_sched_barrier(0);
    if (it + 1 < NT) stageB((it + 1) * 64, (it + 1) & 1);
    if (it + 2 < NT) stageA((it + 2) * 64, (it + 2) % 3);
    const unsigned short* AsB = As[it % 3];
    const unsigned short* BsB = Bs[it & 1];
#pragma unroll
    for (int hh = 0; hh < 2; ++hh) {
      bf16x8 af[2], bf[4];
#pragma unroll
      for (int mi = 0; mi < 2; ++mi)
        af[mi] = *(const bf16x8*)&AsB[(wm * 32 + mi * 16 + lo) * 64 + ((hh * 4 + q4) ^ lo7) * 8];
#pragma unroll
      for (int ni = 0; ni < 4; ++ni)
        bf[ni] = *(const bf16x8*)&BsB[(wn * 64 + ni * 16 + lo) * 64 + ((hh * 4 + q4) ^ lo7) * 8];
#pragma unroll
      for (int mi = 0; mi < 2; ++mi)
#pragma unroll
        for (int ni = 0; ni < 4; ++ni)
          acc[mi][ni] = __builtin_amdgcn_mfma_f32_16x16x32_bf16(af[mi], bf[ni], acc[mi][ni], 0, 0, 0);
    }
  }

  unsigned short* dst = (mid == 0) ? qw : (mid == 1) ? kw : vtw;
  const float sc = (mid == 0) ? C1SCALE : 1.0f;
#pragma unroll
  for (int mi = 0; mi < 2; ++mi) {
#pragma unroll
    for (int ni = 0; ni < 4; ++ni) {
      int m_ = m0 + wm * 32 + mi * 16 + q4 * 4;      // t0 (multiple of 4)
      int nl = ((nb & 7) * 128) + wn * 64 + ni * 16 + lo;
      int b_ = m_ >> 11, t_ = m_ & (TT - 1);
      int h_ = nl >> 6, d_ = nl & 63;
      if (mid == 2) {
        ushort4 o4;
        o4.x = f2bf(acc[mi][ni][0]);
        o4.y = f2bf(acc[mi][ni][1]);
        o4.z = f2bf(acc[mi][ni][2]);
        o4.w = f2bf(acc[mi][ni][3]);
        *(ushort4*)&dst[(((size_t)(b_ * NHEADS + h_)) * HDIM + d_) * TT + t_] = o4;
      } else {
#pragma unroll
        for (int r = 0; r < 4; ++r) {
          float v = acc[mi][ni][r] * sc;
          dst[(((size_t)(b_ * NHEADS + h_)) * TT + t_ + r) * HDIM + d_] = f2bf(v);
        }
      }
    }
  }
}

// Output projection: C = A W^T + bias, fp32 out. Same T4-lite pipeline.
__global__ __launch_bounds__(512, 4) void gemm_out(
    const unsigned short* __restrict__ A, const unsigned short* __restrict__ W,
    const float* __restrict__ bias, float* __restrict__ C)
{
  __shared__ unsigned short As[3][128 * 64];
  __shared__ unsigned short Bs[2][128 * 64];
  const int tid  = threadIdx.x;
  const int lane = tid & 63;
  const int wave = tid >> 6;
  const int lo   = lane & 15, q4 = lane >> 4;
  const int lo7  = lane & 7;
  const int wm   = wave & 3, wn = wave >> 2;
  const int m0 = blockIdx.x * 128, n0 = blockIdx.y * 128;

  f32x4 acc[2][4] = {};

  auto stageA = [&](int k0, int buf) {
#pragma unroll
    for (int i = 0; i < 2; ++i) {
      int ci = i * 512 + tid;
      int row = ci >> 3;
      int c = (ci & 7) ^ (row & 7);
      async16(A + (size_t)(m0 + row) * DMODEL + k0 + c * 8, (char*)As[buf] + ci * 16);
    }
  };
  auto stageB = [&](int k0, int buf) {
#pragma unroll
    for (int i = 0; i < 2; ++i) {
      int ci = i * 512 + tid;
      int row = ci >> 3;
      int c = (ci & 7) ^ (row & 7);
      async16(W + (size_t)(n0 + row) * DMODEL + k0 + c * 8, (char*)Bs[buf] + ci * 16);
    }
  };

  const int NT = DMODEL / 64;
  stageA(0, 0); stageB(0, 0); stageA(64, 1);

  for (int it = 0; it < NT; ++it) {
    if (it + 1 < NT) asm volatile("s_waitcnt vmcnt(2) lgkmcnt(0)" ::: "memory");
    else             asm volatile("s_waitcnt vmcnt(0) lgkmcnt(0)" ::: "memory");
    __builtin_amdgcn_s_barrier();
    __builtin_amdgcn_sched_barrier(0);
    if (it + 1 < NT) stageB((it + 1) * 64, (it + 1) & 1);
    if (it + 2 < NT) stageA((it + 2) * 64, (it + 2) % 3);
    const unsigned short* AsB = As[it % 3];
    const unsigned short* BsB = Bs[it & 1];
#pragma unroll
    for (int hh = 0; hh < 2; ++hh) {
      bf16x8 af[2], bf[4];
#pragma unroll
      for (int mi = 0; mi < 2; ++mi)
        af[mi] = *(const bf16x8*)&AsB[(wm * 32 + mi * 16 + lo) * 64 + ((hh * 4 + q4) ^ lo7) * 8];
#pragma unroll
      for (int ni = 0; ni < 4; ++ni)
        bf[ni] = *(const bf16x8*)&BsB[(wn * 64 + ni * 16 + lo) * 64 + ((hh * 4 + q4) ^ lo7) * 8];
#pragma unroll
      for (int mi = 0; mi < 2; ++mi)
#pragma unroll
        for (int ni = 0; ni < 4; ++ni)
          acc[mi][ni] = __builtin_amdgcn_mfma_f32_16x16x32_bf16(af[mi], bf[ni], acc[mi][ni], 0, 0, 0);
    }
  }

#pragma unroll
  for (int mi = 0; mi < 2; ++mi)
#pragma unroll
    for (int ni = 0; ni < 4; ++ni)
#pragma unroll
      for (int r = 0; r < 4; ++r) {
        int m = m0 + wm * 32 + mi * 16 + q4 * 4 + r;
        int n = n0 + wn * 64 + ni * 16 + lo;
        C[(size_t)m * DMODEL + n] = acc[mi][ni][r] + bias[n];
      }
}

// Flash attention + ALiBi, fixed-scale softmax, register-resident P (S^T trick),
// exact per-head sliding window. 8 waves x 32 q-rows = 256-row Q-block.
// Inner stage/compute bodies byte-identical to the r5-verified kernel.
// QUAD-buffered pair loop (one barrier per 2 tiles). Window = 16 exp2-bits
// (11.094 = 16/log2(e)). LDS 64 KB, 2 blocks/CU.
__global__ __launch_bounds__(512, 4) void attn_kernel(
    const unsigned short* __restrict__ Q, const unsigned short* __restrict__ K,
    const unsigned short* __restrict__ Vt, unsigned short* __restrict__ O)
{
  __shared__ unsigned short Ks[4][64 * 64];
  __shared__ unsigned short Vs[4][64 * 64];

  const int tid = threadIdx.x, lane = tid & 63, wave = tid >> 6;  // wave 0..7
  const int lo = lane & 15, q4 = lane >> 4;
  const int lo7 = lane & 7;
  const int bid = blockIdx.x;  // 512 blocks
  // XCD-group decomposition: g = (bid&7) + 8*(bid>>6), qb = (bid>>3)&7
  const int g   = (bid & 7) + 8 * (bid >> 6);   // 0..63 group (slot,b)
  const int qb  = (bid >> 3) & 7;
  const int slot = g >> 2;
  const int b   = g & 3;
  // htab[s] packed as nibbles: {12,13,14,15,11,10,9,8,4,5,6,7,1,0,2,3}
  const int h  = (int)((0x3201765489ABFEDCull >> (slot * 4)) & 15);
  const int bh = b * NHEADS + h;
  const float slopeL = exp2f(-0.5f * (float)(h + 1)) * 1.44269504f;
  const int q0 = qb * 256;
  const int wq0 = q0 + wave * 32;

  // per-head window: keep tiles with min distance <= D = 16 exp2-bits
  const int D = (int)(11.094f * exp2f(0.5f * (float)(h + 1)));
  int tlo = q0 - D;
  const int ktlo = (tlo <= 0) ? 0 : (tlo >> 6);
  int thi = (q0 + 255 + D) >> 6;
  const int kthi = (thi > TT / 64 - 1) ? TT / 64 - 1 : thi;

  // Q fragments (B-operand of S^T): 2 m-tiles x 2 k-halves
  bf16x8 qf[2][2];
#pragma unroll
  for (int m = 0; m < 2; ++m)
#pragma unroll
    for (int hh = 0; hh < 2; ++hh)
      qf[m][hh] = *(const bf16x8*)(Q + ((size_t)bh * TT + wq0 + m * 16 + lo) * HDIM + hh * 32 + q4 * 8);

  f32x4 Oacc[2][4];
  float ps[2] = {0.f, 0.f};            // f32 row-sum (qrow = lo), per m-tile
#pragma unroll
  for (int m = 0; m < 2; ++m)
#pragma unroll
    for (int nd = 0; nd < 4; ++nd) Oacc[m][nd] = f32x4{0.f, 0.f, 0.f, 0.f};

  // hoisted distance base: qrow - key = eb[m][r] - (kt*64 + ns*16)
  float eb[2][4];
#pragma unroll
  for (int m = 0; m < 2; ++m)
#pragma unroll
    for (int r = 0; r < 4; ++r)
      eb[m][r] = (float)(wq0 + m * 16 + lo - q4 * 4 - r);

  const unsigned short* kbh = K + (size_t)bh * TT * HDIM;
  const unsigned short* vbh = Vt + (size_t)bh * HDIM * TT;

  // 512 threads: exactly one 16B chunk per thread per array per 64-key tile
  auto stage = [&](int kt, int buf) {
    int ci = tid;                      // 0..511
    int row = ci >> 3;
    int c = (ci & 7) ^ (row & 7);
    async16(kbh + (size_t)(kt * 64 + row) * HDIM + c * 8, (char*)Ks[buf] + ci * 16);
    async16(vbh + (size_t)row * TT + kt * 64 + c * 8,     (char*)Vs[buf] + ci * 16);
  };

  // r5-verified per-tile compute (2 x 32-key phases)
  auto compute = [&](int kt, int buf) {
#pragma unroll
    for (int pp = 0; pp < 2; ++pp) {       // 32-key half-tiles
      unsigned int ua[2][2], ub[2][2];     // [hns][m]: packed words (r0,r1)/(r2,r3)
#pragma unroll
      for (int hns = 0; hns < 2; ++hns) {
        const int ns = pp * 2 + hns;
        const int krow = (ns * 16 + lo) * 64;
        bf16x8 kf0 = *(const bf16x8*)&Ks[buf][krow + ((q4) ^ lo7) * 8];
        bf16x8 kf1 = *(const bf16x8*)&Ks[buf][krow + ((4 + q4) ^ lo7) * 8];
        const float kb = (float)(kt * 64 + ns * 16);
#pragma unroll
        for (int m = 0; m < 2; ++m) {
          // S^T: D[key][qrow], lane: col=lo=qrow, rows=q4*4+r=key-in-block
          f32x4 a = {0.f, 0.f, 0.f, 0.f};
          __builtin_amdgcn_s_setprio(1);
          a = __builtin_amdgcn_mfma_f32_16x16x32_bf16(kf0, qf[m][0], a, 0, 0, 0);
          a = __builtin_amdgcn_mfma_f32_16x16x32_bf16(kf1, qf[m][1], a, 0, 0, 0);
          __builtin_amdgcn_s_setprio(0);
          float pv[4];
#pragma unroll
          for (int r = 0; r < 4; ++r) {
            float w = eb[m][r] - kb;                      // qrow - key
            pv[r] = EXP2(fmaf(-slopeL, fabsf(w), a[r]));  // a already scaled by c1
          }
          ps[m] += (pv[0] + pv[1]) + (pv[2] + pv[3]);     // VALU row-sum
          ua[hns][m] = pkbf_rne(pv[0], pv[1]);
          ub[hns][m] = pkbf_rne(pv[2], pv[3]);
        }
      }

      // lane-group transpose: (q4'*4+r keys) -> (q4*8+j keys) K=32 A-fragment
      bf16x8 paf[2];
#pragma unroll
      for (int m = 0; m < 2; ++m) {
        unsigned int w0 = ua[0][m], w2 = ua[1][m];
        unsigned int w1 = ub[0][m], w3 = ub[1][m];
        asm("v_permlane32_swap_b32 %0, %1" : "+v"(w0), "+v"(w2));
        asm("v_permlane16_swap_b32 %0, %1" : "+v"(w0), "+v"(w2));  // w0=W0 w2=W2
        asm("v_permlane32_swap_b32 %0, %1" : "+v"(w1), "+v"(w3));
        asm("v_permlane16_swap_b32 %0, %1" : "+v"(w1), "+v"(w3));  // w1=W1 w3=W3
        union { bf16x8 v; unsigned int u[4]; } U;
        U.u[0] = w0; U.u[1] = w1; U.u[2] = w2; U.u[3] = w3;
        paf[m] = U.v;
      }

      // PV at K=32; B = Vt rows (n=d, k=key in 32-key half-tile)
#pragma unroll
      for (int nd = 0; nd < 4; ++nd) {
        const int row = nd * 16 + lo;
        bf16x8 vb = *(const bf16x8*)&Vs[buf][row * 64 + ((pp * 4 + q4) ^ lo7) * 8];
        __builtin_amdgcn_s_setprio(1);
#pragma unroll
        for (int m = 0; m < 2; ++m)
          Oacc[m][nd] = __builtin_amdgcn_mfma_f32_16x16x32_bf16(paf[m], vb, Oacc[m][nd], 0, 0, 0);
        __builtin_amdgcn_s_setprio(0);
      }
    }
  };

  // quad-buffered pair loop: one barrier per 2 tiles
  stage(ktlo, 0);
  if (ktlo + 1 <= kthi) stage(ktlo + 1, 1);
  int kt = ktlo;
  for (; kt + 1 <= kthi; kt += 2) {
    const int b0 = (kt - ktlo) & 3;
    __syncthreads();  // tiles kt, kt+1 resident; prev pair's buffers free
    if (kt + 2 <= kthi) stage(kt + 2, (b0 + 2) & 3);
    if (kt + 3 <= kthi) stage(kt + 3, (b0 + 3) & 3);
    compute(kt, b0);
    compute(kt + 1, (b0 + 1) & 3);
  }
  if (kt <= kthi) {  // odd tail
    __syncthreads();
    compute(kt, (kt - ktlo) & 3);
  }

  // reduce row-sums across the 4 q4 lane-groups (qrow = lo after reduction)
#pragma unroll
  for (int m = 0; m < 2; ++m) {
    ps[m] += __shfl_xor(ps[m], 16);
    ps[m] += __shfl_xor(ps[m], 32);
  }

  // epilogue: fetch row-sum for qrow=q4*4+r from lane (q4*4+r), normalize, store
#pragma unroll
  for (int m = 0; m < 2; ++m)
#pragma unroll
    for (int r = 0; r < 4; ++r) {
      float l = __shfl(ps[m], q4 * 4 + r);
      float inv = 1.f / l;
      int t = wq0 + m * 16 + q4 * 4 + r;
#pragma unroll
      for (int nd = 0; nd < 4; ++nd) {
        int d = nd * 16 + lo;
        O[((size_t)(b * TT + t)) * DMODEL + h * HDIM + d] = f2bf(Oacc[m][nd][r] * inv);
      }
    }
}

extern "C" void kernel_launch(void* const* d_in, const int* in_sizes, int n_in,
                              void* d_out, int out_size, void* d_ws, size_t ws_size,
                              hipStream_t stream) {
  const float* x  = (const float*)d_in[0];
  const float* wq = (const float*)d_in[1];
  const float* wk = (const float*)d_in[2];
  const float* wv = (const float*)d_in[3];
  const float* wo = (const float*)d_in[4];
  const float* bo = (const float*)d_in[5];
  float* out = (float*)d_out;

  char* ws = (char*)d_ws;
  const size_t seg  = (size_t)BB * TT * DMODEL * sizeof(unsigned short);  // 16.78 MB
  const size_t wseg = (size_t)DMODEL * DMODEL * sizeof(unsigned short);   // 2 MB
  unsigned short* qw    = (unsigned short*)(ws);
  unsigned short* kw    = (unsigned short*)(ws + seg);
  unsigned short* vtw   = (unsigned short*)(ws + 2 * seg);
  unsigned short* ow    = (unsigned short*)(ws + 3 * seg);
  unsigned short* xb    = (unsigned short*)(ws + 4 * seg);
  unsigned short* wqkvb = (unsigned short*)(ws + 5 * seg);
  unsigned short* wob   = (unsigned short*)(ws + 5 * seg + 3 * wseg);

  cvt_all<<<dim3(8192 + 4096), dim3(256), 0, stream>>>(x, wq, wk, wv, wo, xb, wqkvb, wob);

  gemm_qkv<<<dim3(64, 24), dim3(512), 0, stream>>>(xb, wqkvb, qw, kw, vtw);

  attn_kernel<<<dim3(BB * NHEADS * (TT / 256)), dim3(512), 0, stream>>>(qw, kw, vtw, ow);

  gemm_out<<<dim3(64, 8), dim3(512), 0, stream>>>(ow, wob, bo, out);
}